// Round 20
// baseline (285.313 us; speedup 1.0000x reference)
//
#include <hip/hip_runtime.h>
#include <hip/hip_bf16.h>
#include <cstdint>

#define C_DIM 128
#define E_DIM 64
#define B_DIM 8192

typedef __attribute__((ext_vector_type(8))) short short8;
typedef __attribute__((ext_vector_type(4))) float f32x4;

union Frag8 { short8 v; short s[8]; uint32_t u[4]; };

__device__ __forceinline__ unsigned short bfbits(float x) {
    union { __hip_bfloat16 h; unsigned short u; } cv;
    cv.h = __float2bfloat16(x);
    return cv.u;
}
__device__ __forceinline__ float bits2f(unsigned short b) {
    return __uint_as_float(((uint32_t)b) << 16);
}

// ---------- K0: w = softmax(q,axis=1), zero diag, split hi/lo bf16, layout [c][n] ----------
__global__ __launch_bounds__(128) void k0_softmax(const float* __restrict__ q,
                                                  unsigned short* __restrict__ whi,
                                                  unsigned short* __restrict__ wlo) {
    const int c = blockIdx.x;
    const int t = threadIdx.x;            // n
    __shared__ float redM[2], redS[2];
    float v = q[c * C_DIM + t];
    float m = v;
    #pragma unroll
    for (int o = 32; o > 0; o >>= 1) m = fmaxf(m, __shfl_xor(m, o));
    if ((t & 63) == 0) redM[t >> 6] = m;
    __syncthreads();
    m = fmaxf(redM[0], redM[1]);
    float e = expf(v - m);
    float s = e;
    #pragma unroll
    for (int o = 32; o > 0; o >>= 1) s += __shfl_xor(s, o);
    if ((t & 63) == 0) redS[t >> 6] = s;
    __syncthreads();
    s = redS[0] + redS[1];
    float w = e / s;
    if (t == c) w = 0.f;                  // zero diagonal AFTER softmax
    unsigned short hb = bfbits(w);
    whi[c * C_DIM + t] = hb;
    wlo[c * C_DIM + t] = bfbits(w - bits2f(hb));
}

// ---------- KP: elementwise hi/lo bf16 split of a f32 weight tensor ----------
__global__ __launch_bounds__(256) void kP_split(const float* __restrict__ src,
                                                unsigned short* __restrict__ hi,
                                                unsigned short* __restrict__ lo) {
    const int i = blockIdx.x * 256 + threadIdx.x;   // index in float4 units
    const float4 v = ((const float4*)src)[i];
    float f[4] = {v.x, v.y, v.z, v.w};
    unsigned short h[4], l[4];
    #pragma unroll
    for (int j = 0; j < 4; ++j) {
        h[j] = bfbits(f[j]);
        l[j] = bfbits(f[j] - bits2f(h[j]));
    }
    ((ushort4*)hi)[i] = make_ushort4(h[0], h[1], h[2], h[3]);
    ((ushort4*)lo)[i] = make_ushort4(l[0], l[1], l[2], l[3]);
}

// ---------- K1: value MLP + L2 norm, MFMA. Output V[r][n8][e][8n] bf16 ----------
// block = 64 rows x 8 columns, 8 waves (1 column each). D: m=r, n=f.
// W2 hi-only; repack XOR-spreads banks; readout un-permutes (R16-verified).
__global__ __launch_bounds__(512, 4) void k1_value(
        const float* __restrict__ samples, const float* __restrict__ W1,
        const float* __restrict__ b1, const unsigned short* __restrict__ W2hi,
        const float* __restrict__ b2,
        uint32_t* __restrict__ vbuf, int rowOff) {
    __shared__ char sOut[32 * 1024];       // [r32][f][c_local] bf16, XOR-swizzled
    const int t = threadIdx.x;
    const int rt = blockIdx.x, cg = blockIdx.y;
    const int r0 = rt * 64;
    const int cl = t >> 6;                 // wave = local column
    const int lane = t & 63;
    const int lm = lane & 15, lg = lane >> 4;
    const int c = cg * 8 + cl;
    // per-thread bank-spread XOR: bit2 = f&8 (= lane&8), bit3 = rl&8 (= lg bit1)
    const uint32_t xb = (((uint32_t)lane & 8u) >> 1) | ((((uint32_t)lane >> 5) & 1u) << 3);

    // scatter sample loads issued first (deepest latency)
    float sv[4];
    #pragma unroll
    for (int mt = 0; mt < 4; ++mt)
        sv[mt] = samples[(size_t)(rowOff + r0 + mt * 16 + lm) * C_DIM + c];

    float b2r[4];
    #pragma unroll
    for (int nt = 0; nt < 4; ++nt) b2r[nt] = b2[(size_t)c * 64 + nt * 16 + lm];

    f32x4 acc[4][4];
    #pragma unroll
    for (int mt = 0; mt < 4; ++mt)
        #pragma unroll
        for (int nt = 0; nt < 4; ++nt)
            acc[mt][nt] = (f32x4){0.f, 0.f, 0.f, 0.f};

    #pragma unroll
    for (int ks = 0; ks < 2; ++ks) {
        const size_t wbase = ((size_t)c * 64) * 64 + ks * 32 + lg * 8;

        // rotating double-buffer of B-frags (hi only; static names, rule #20)
        short8 bhA = *(const short8*)(W2hi + wbase + (size_t)(0 * 16 + lm) * 64);
        short8 bhB = *(const short8*)(W2hi + wbase + (size_t)(1 * 16 + lm) * 64);

        // W1/b1 slices for this ks (k-contiguous 8 elems)
        const float4 w1a = *(const float4*)(W1 + (size_t)c * 64 + ks * 32 + lg * 8);
        const float4 w1b = *(const float4*)(W1 + (size_t)c * 64 + ks * 32 + lg * 8 + 4);
        const float4 b1a = *(const float4*)(b1 + (size_t)c * 64 + ks * 32 + lg * 8);
        const float4 b1b = *(const float4*)(b1 + (size_t)c * 64 + ks * 32 + lg * 8 + 4);
        const float w1r[8] = {w1a.x, w1a.y, w1a.z, w1a.w, w1b.x, w1b.y, w1b.z, w1b.w};
        const float b1r[8] = {b1a.x, b1a.y, b1a.z, b1a.w, b1b.x, b1b.y, b1b.z, b1b.w};

        // A-frags (VALU work overlaps the in-flight B loads)
        short8 afr[4];
        #pragma unroll
        for (int mt = 0; mt < 4; ++mt) {
            Frag8 af;
            #pragma unroll
            for (int j = 0; j < 8; ++j)
                af.s[j] = (short)bfbits(fmaxf(fmaf(sv[mt], w1r[j], b1r[j]), 0.f));
            afr[mt] = af.v;
        }

        // explicit schedule: MFMA(cur) then prefetch(next)
        {
            #pragma unroll
            for (int mt = 0; mt < 4; ++mt)
                acc[mt][0] = __builtin_amdgcn_mfma_f32_16x16x32_bf16(afr[mt], bhA, acc[mt][0], 0, 0, 0);
            bhA = *(const short8*)(W2hi + wbase + (size_t)(2 * 16 + lm) * 64);

            #pragma unroll
            for (int mt = 0; mt < 4; ++mt)
                acc[mt][1] = __builtin_amdgcn_mfma_f32_16x16x32_bf16(afr[mt], bhB, acc[mt][1], 0, 0, 0);
            bhB = *(const short8*)(W2hi + wbase + (size_t)(3 * 16 + lm) * 64);

            #pragma unroll
            for (int mt = 0; mt < 4; ++mt)
                acc[mt][2] = __builtin_amdgcn_mfma_f32_16x16x32_bf16(afr[mt], bhA, acc[mt][2], 0, 0, 0);

            #pragma unroll
            for (int mt = 0; mt < 4; ++mt)
                acc[mt][3] = __builtin_amdgcn_mfma_f32_16x16x32_bf16(afr[mt], bhB, acc[mt][3], 0, 0, 0);
        }
    }

    // add b2, sum of squares over f (lane-local over nt, butterfly over lm lanes)
    float rsc[4][4];
    #pragma unroll
    for (int mt = 0; mt < 4; ++mt)
        #pragma unroll
        for (int i = 0; i < 4; ++i) {
            float s2 = 0.f;
            #pragma unroll
            for (int nt = 0; nt < 4; ++nt) {
                float vv = acc[mt][nt][i] + b2r[nt];
                acc[mt][nt][i] = vv;
                s2 = fmaf(vv, vv, s2);
            }
            s2 += __shfl_xor(s2, 1); s2 += __shfl_xor(s2, 2);
            s2 += __shfl_xor(s2, 4); s2 += __shfl_xor(s2, 8);
            rsc[mt][i] = 1.f / fmaxf(sqrtf(s2), 1e-12f);
        }

    // two 32-row passes: repack into 32KB LDS, then coalesced writeout
    #pragma unroll
    for (int p = 0; p < 2; ++p) {
        if (p) __syncthreads();            // protect previous readout
        #pragma unroll
        for (int mh = 0; mh < 2; ++mh) {
            const int mt = p * 2 + mh;
            #pragma unroll
            for (int i = 0; i < 4; ++i) {
                const int rl = mh * 16 + lg * 4 + i;      // local row 0..31
                const uint32_t rowbase = (uint32_t)rl * 1024u;
                const uint32_t swz = (uint32_t)(rl & 7) << 4;
                #pragma unroll
                for (int nt = 0; nt < 4; ++nt) {
                    const int f = nt * 16 + lm;
                    const uint32_t bo = (rowbase + (uint32_t)f * 16u + (uint32_t)cl * 2u) ^ swz ^ xb;
                    *(unsigned short*)(sOut + bo) = bfbits(acc[mt][nt][i] * rsc[mt][i]);
                }
            }
        }
        __syncthreads();
        #pragma unroll
        for (int it = 0; it < 4; ++it) {
            const int unit = t + it * 512;
            const int rl = unit >> 6, f = unit & 63;
            const uint32_t lb = ((uint32_t)rl * 1024u + (uint32_t)f * 16u) ^ ((uint32_t)(rl & 7) << 4);
            uint4 val = *(const uint4*)(sOut + lb);
            // undo intra-unit XOR permutation (word j holds logical word j^sw):
            // sw bit1 = rl&8 (== it&1, compile-time), sw bit0 = f&8 (== t&8, per-lane)
            if (it & 1) val = make_uint4(val.z, val.w, val.x, val.y);
            {
                const bool s0 = (t & 8) != 0;
                const uint32_t a = s0 ? val.y : val.x;
                const uint32_t b = s0 ? val.x : val.y;
                const uint32_t cc2 = s0 ? val.w : val.z;
                const uint32_t d = s0 ? val.z : val.w;
                val = make_uint4(a, b, cc2, d);
            }
            ((uint4*)vbuf)[((size_t)(r0 + p * 32 + rl) * 16 + cg) * 64 + f] = val;
        }
    }
}

// ---------- K2: ctx GEMM, N-split (R14-verified core); writeout to k3-fragment
// layout ctx2[c][rtile][r&15][e] (128B per (c,row), e linear) so k3 needs no LDS.
__global__ __launch_bounds__(512) void k2_ctx(
        const unsigned short* __restrict__ whi,
        const uint32_t* __restrict__ vbuf, uint32_t* __restrict__ cbuf, int nrt) {
    __shared__ char sC[65536];             // 4 rows x 16 KB
    const int t = threadIdx.x;
    const int lane = t & 63, wv = t >> 6;
    const int lm = lane & 15, lg = lane >> 4;
    const int rloc = wv >> 1, ch = wv & 1;
    const size_t rbase = (size_t)blockIdx.x * 4;
    const size_t r = rbase + rloc;
    const char* vrow = (const char*)vbuf + (r << 14);

#define LDA(KS, ET) (*(const short8*)(vrow + ((KS) * 4 + lg) * 1024 + ((ET) * 16 + lm) * 16))
#define LDW(KS, NT) (*(const short8*)(whi + (size_t)(ch * 64 + (NT) * 16 + lm) * C_DIM + (KS) * 32 + lg * 8))

    f32x4 acc[4][4];                       // [et][nt] -> 64 AGPRs
    #pragma unroll
    for (int et = 0; et < 4; ++et)
        #pragma unroll
        for (int nt = 0; nt < 4; ++nt)
            acc[et][nt] = (f32x4){0.f, 0.f, 0.f, 0.f};

    // A double-buffer (static names), w single-buffer
    short8 afX[4], afY[4], w0[4];
    #pragma unroll
    for (int et = 0; et < 4; ++et) afX[et] = LDA(0, et);
    #pragma unroll
    for (int et = 0; et < 4; ++et) afY[et] = LDA(1, et);
    #pragma unroll
    for (int nt = 0; nt < 4; ++nt) w0[nt] = LDW(0, nt);

#define K2_MFMA(AF)                                                                        \
    _Pragma("unroll")                                                                      \
    for (int nt = 0; nt < 4; ++nt)                                                         \
        _Pragma("unroll")                                                                  \
        for (int et = 0; et < 4; ++et)                                                     \
            acc[et][nt] = __builtin_amdgcn_mfma_f32_16x16x32_bf16(AF[et], w0[nt],          \
                                                                  acc[et][nt], 0, 0, 0);
    // ks = 0
    K2_MFMA(afX)
    #pragma unroll
    for (int et = 0; et < 4; ++et) afX[et] = LDA(2, et);
    #pragma unroll
    for (int nt = 0; nt < 4; ++nt) w0[nt] = LDW(1, nt);
    // ks = 1
    K2_MFMA(afY)
    #pragma unroll
    for (int et = 0; et < 4; ++et) afY[et] = LDA(3, et);
    #pragma unroll
    for (int nt = 0; nt < 4; ++nt) w0[nt] = LDW(2, nt);
    // ks = 2
    K2_MFMA(afX)
    #pragma unroll
    for (int nt = 0; nt < 4; ++nt) w0[nt] = LDW(3, nt);
    // ks = 3
    K2_MFMA(afY)
#undef K2_MFMA
#undef LDA
#undef LDW

    // stage ctx into LDS: [rloc][c][e] bf16, byte ^= ((c&7)<<4)
    char* srow = sC + rloc * 16384;
    #pragma unroll
    for (int et = 0; et < 4; ++et)
        #pragma unroll
        for (int nt = 0; nt < 4; ++nt) {
            const int cloc = ch * 64 + nt * 16 + lm;
            const uint32_t u0 = (uint32_t)bfbits(acc[et][nt][0]) | ((uint32_t)bfbits(acc[et][nt][1]) << 16);
            const uint32_t u1 = (uint32_t)bfbits(acc[et][nt][2]) | ((uint32_t)bfbits(acc[et][nt][3]) << 16);
            uint32_t bo = (uint32_t)cloc * 128u + (uint32_t)(et * 16 + lg * 4) * 2u;
            bo ^= (uint32_t)(cloc & 7) << 4;
            *(uint2*)(srow + bo) = make_uint2(u0, u1);
        }
    __syncthreads();

    // writeout to ctx2[c][rtile][r&15][e]: 8 threads per (c,row) emit 128B contiguous
    #pragma unroll
    for (int it = 0; it < 8; ++it) {
        const int unit = t + it * 512;             // 4096 16B-units in block tile
        const int row = unit >> 10;                // 1024 units per row
        const int u = unit & 1023;                 // c = u>>3, echunk = u&7
        const int cc = u >> 3, ec = u & 7;
        const uint32_t lb = (uint32_t)row * 16384u +
                            (((uint32_t)u * 16u) ^ (((uint32_t)cc & 7u) << 4));
        const uint4 val = *(const uint4*)(sC + lb);
        const size_t grow = rbase + row;
        ((uint4*)cbuf)[(((size_t)cc * nrt + (grow >> 4)) * 16 + (grow & 15)) * 8 + ec] = val;
    }
}

// ---------- K3: out = P2 . relu(P1 @ ctx + pb1) + pb2 — NO LDS, pure streaming ----------
// wave = (c, 16-row tile): A-frags are direct global loads from ctx2 (sector-perfect);
// no barrier, no staging; occupancy limited only by VGPR. block = 8 waves, same c.
__global__ __launch_bounds__(512, 4) void k3_out(
        const uint32_t* __restrict__ cbuf, const unsigned short* __restrict__ P1hi,
        const unsigned short* __restrict__ P1lo, const float* __restrict__ pb1,
        const float* __restrict__ P2, const float* __restrict__ pb2,
        float* __restrict__ out, int rowOff, int nrt) {
    const int t = threadIdx.x;
    const int lane = t & 63, wv = t >> 6;
    const int lm = lane & 15, lg = lane >> 4;
    const int c = blockIdx.x;
    const int rtile = blockIdx.y * 8 + wv;

    // A-fragment base for this (c, rtile): row = lm, e-chunk = lg (+ ks*64 bytes)
    const char* abase = (const char*)cbuf +
        (((size_t)c * nrt + rtile) * 16 + lm) * 128 + (size_t)lg * 16;
    const short8 a0 = *(const short8*)(abase);        // ks = 0
    const short8 a1 = *(const short8*)(abase + 64);   // ks = 1

    float pb1r[4], p2r[4];
    #pragma unroll
    for (int nt = 0; nt < 4; ++nt) {
        pb1r[nt] = pb1[(size_t)c * 64 + nt * 16 + lm];
        p2r[nt]  = P2[(size_t)c * 64 + nt * 16 + lm];
    }
    const float pb2c = pb2[c];

    f32x4 acc[4];                           // [nt]
    #pragma unroll
    for (int nt = 0; nt < 4; ++nt) acc[nt] = (f32x4){0.f, 0.f, 0.f, 0.f};

    #pragma unroll
    for (int nt = 0; nt < 4; ++nt) {
        const size_t wb0 = ((size_t)c * 64 + nt * 16 + lm) * 64 + 0 * 32 + lg * 8;
        const size_t wb1 = ((size_t)c * 64 + nt * 16 + lm) * 64 + 1 * 32 + lg * 8;
        const short8 bh0 = *(const short8*)(P1hi + wb0);
        const short8 bl0 = *(const short8*)(P1lo + wb0);
        const short8 bh1 = *(const short8*)(P1hi + wb1);
        const short8 bl1 = *(const short8*)(P1lo + wb1);
        acc[nt] = __builtin_amdgcn_mfma_f32_16x16x32_bf16(a0, bh0, acc[nt], 0, 0, 0);
        acc[nt] = __builtin_amdgcn_mfma_f32_16x16x32_bf16(a0, bl0, acc[nt], 0, 0, 0);
        acc[nt] = __builtin_amdgcn_mfma_f32_16x16x32_bf16(a1, bh1, acc[nt], 0, 0, 0);
        acc[nt] = __builtin_amdgcn_mfma_f32_16x16x32_bf16(a1, bl1, acc[nt], 0, 0, 0);
    }

    // epilogue: relu, dot with P2 over f (lane-local nt + butterfly over lm), store
    #pragma unroll
    for (int i = 0; i < 4; ++i) {
        float p = 0.f;
        #pragma unroll
        for (int nt = 0; nt < 4; ++nt)
            p = fmaf(fmaxf(acc[nt][i] + pb1r[nt], 0.f), p2r[nt], p);
        p += __shfl_xor(p, 1); p += __shfl_xor(p, 2);
        p += __shfl_xor(p, 4); p += __shfl_xor(p, 8);
        if (lm == 0)
            out[(size_t)(rowOff + rtile * 16 + lg * 4 + i) * C_DIM + c] = p + pb2c;
    }
}

// ---------- host ----------
extern "C" void kernel_launch(void* const* d_in, const int* in_sizes, int n_in,
                              void* d_out, int out_size, void* d_ws, size_t ws_size,
                              hipStream_t stream) {
    const float* samples = (const float*)d_in[0];
    const float* W1  = (const float*)d_in[1];
    const float* b1  = (const float*)d_in[2];
    const float* W2  = (const float*)d_in[3];
    const float* b2  = (const float*)d_in[4];
    const float* q   = (const float*)d_in[5];
    const float* P1  = (const float*)d_in[6];
    const float* pb1 = (const float*)d_in[7];
    const float* P2  = (const float*)d_in[8];
    const float* pb2 = (const float*)d_in[9];
    float* out = (float*)d_out;

    char* ws = (char*)d_ws;
    unsigned short* whi  = (unsigned short*)ws;                       // 32KB
    unsigned short* wlo  = (unsigned short*)(ws + 32768);             // 32KB (k0 side product)
    unsigned short* W2hi = (unsigned short*)(ws + 65536);             // 1MB
    unsigned short* W2lo = (unsigned short*)(ws + 65536 + 1048576);   // 1MB (unused by k1 now)
    unsigned short* P1hi = (unsigned short*)(ws + 65536 + 2097152);   // 1MB
    unsigned short* P1lo = (unsigned short*)(ws + 65536 + 3145728);   // 1MB
    const size_t head = 65536 + 4194304;

    // two regions: V and ctx, each maxRows*16KB (full-batch chunking, R14 best)
    size_t avail = (ws_size > head) ? ws_size - head : 0;
    long maxRows = (long)(avail / ((size_t)2 * C_DIM * E_DIM * 2));
    maxRows = (maxRows / 256) * 256;
    if (maxRows > B_DIM) maxRows = B_DIM;
    if (maxRows < 256) maxRows = 256;

    uint32_t* vbuf = (uint32_t*)(ws + head);
    uint32_t* cbuf = (uint32_t*)(ws + head + (size_t)maxRows * 16384);

    k0_softmax<<<dim3(C_DIM), dim3(C_DIM), 0, stream>>>(q, whi, wlo);
    kP_split<<<dim3(512), 256, 0, stream>>>(W2, W2hi, W2lo);   // 524288 floats / 4 / 256
    kP_split<<<dim3(512), 256, 0, stream>>>(P1, P1hi, P1lo);

    for (int off = 0; off < B_DIM; off += (int)maxRows) {
        const int rows = (int)(((long)(B_DIM - off) < maxRows) ? (long)(B_DIM - off) : maxRows);
        const int nrt = rows / 16;
        k1_value<<<dim3(rows / 64, 16), 512, 0, stream>>>(samples, W1, b1, W2hi, b2, vbuf, off);
        k2_ctx<<<dim3(rows / 4), 512, 0, stream>>>(whi, vbuf, cbuf, nrt);
        k3_out<<<dim3(C_DIM, rows / 128), 512, 0, stream>>>(cbuf, P1hi, P1lo, pb1, P2, pb2, out, off, nrt);
    }
}

// Round 21
// 221.682 us; speedup vs baseline: 1.2870x; 1.2870x over previous
//
#include <hip/hip_runtime.h>
#include <hip/hip_bf16.h>
#include <cstdint>

#define C_DIM 128
#define E_DIM 64
#define B_DIM 8192

typedef __attribute__((ext_vector_type(8))) short short8;
typedef __attribute__((ext_vector_type(4))) float f32x4;

union Frag8 { short8 v; short s[8]; uint32_t u[4]; };

__device__ __forceinline__ unsigned short bfbits(float x) {
    union { __hip_bfloat16 h; unsigned short u; } cv;
    cv.h = __float2bfloat16(x);
    return cv.u;
}
__device__ __forceinline__ float bits2f(unsigned short b) {
    return __uint_as_float(((uint32_t)b) << 16);
}

// ---------- K0: w = softmax(q,axis=1), zero diag, split hi/lo bf16, layout [c][n] ----------
__global__ __launch_bounds__(128) void k0_softmax(const float* __restrict__ q,
                                                  unsigned short* __restrict__ whi,
                                                  unsigned short* __restrict__ wlo) {
    const int c = blockIdx.x;
    const int t = threadIdx.x;            // n
    __shared__ float redM[2], redS[2];
    float v = q[c * C_DIM + t];
    float m = v;
    #pragma unroll
    for (int o = 32; o > 0; o >>= 1) m = fmaxf(m, __shfl_xor(m, o));
    if ((t & 63) == 0) redM[t >> 6] = m;
    __syncthreads();
    m = fmaxf(redM[0], redM[1]);
    float e = expf(v - m);
    float s = e;
    #pragma unroll
    for (int o = 32; o > 0; o >>= 1) s += __shfl_xor(s, o);
    if ((t & 63) == 0) redS[t >> 6] = s;
    __syncthreads();
    s = redS[0] + redS[1];
    float w = e / s;
    if (t == c) w = 0.f;                  // zero diagonal AFTER softmax
    unsigned short hb = bfbits(w);
    whi[c * C_DIM + t] = hb;
    wlo[c * C_DIM + t] = bfbits(w - bits2f(hb));
}

// ---------- KP: elementwise hi/lo bf16 split of a f32 weight tensor ----------
__global__ __launch_bounds__(256) void kP_split(const float* __restrict__ src,
                                                unsigned short* __restrict__ hi,
                                                unsigned short* __restrict__ lo) {
    const int i = blockIdx.x * 256 + threadIdx.x;   // index in float4 units
    const float4 v = ((const float4*)src)[i];
    float f[4] = {v.x, v.y, v.z, v.w};
    unsigned short h[4], l[4];
    #pragma unroll
    for (int j = 0; j < 4; ++j) {
        h[j] = bfbits(f[j]);
        l[j] = bfbits(f[j] - bits2f(h[j]));
    }
    ((ushort4*)hi)[i] = make_ushort4(h[0], h[1], h[2], h[3]);
    ((ushort4*)lo)[i] = make_ushort4(l[0], l[1], l[2], l[3]);
}

// ---------- KPh: hi-only bf16 cast (W2: lo half unused since R16) ----------
__global__ __launch_bounds__(256) void kP_hi(const float* __restrict__ src,
                                             unsigned short* __restrict__ hi) {
    const int i = blockIdx.x * 256 + threadIdx.x;   // index in float4 units
    const float4 v = ((const float4*)src)[i];
    ((ushort4*)hi)[i] = make_ushort4(bfbits(v.x), bfbits(v.y), bfbits(v.z), bfbits(v.w));
}

// ---------- K1: value MLP + L2 norm, MFMA. Output V[r][n8][e][8n] bf16 ----------
// block = 64 rows x 8 columns, 8 waves (1 column each). D: m=r, n=f.
// W2 hi-only; repack XOR-spreads banks; readout un-permutes (R16-verified).
__global__ __launch_bounds__(512, 4) void k1_value(
        const float* __restrict__ samples, const float* __restrict__ W1,
        const float* __restrict__ b1, const unsigned short* __restrict__ W2hi,
        const float* __restrict__ b2,
        uint32_t* __restrict__ vbuf, int rowOff) {
    __shared__ char sOut[32 * 1024];       // [r32][f][c_local] bf16, XOR-swizzled
    const int t = threadIdx.x;
    const int rt = blockIdx.x, cg = blockIdx.y;
    const int r0 = rt * 64;
    const int cl = t >> 6;                 // wave = local column
    const int lane = t & 63;
    const int lm = lane & 15, lg = lane >> 4;
    const int c = cg * 8 + cl;
    // per-thread bank-spread XOR: bit2 = f&8 (= lane&8), bit3 = rl&8 (= lg bit1)
    const uint32_t xb = (((uint32_t)lane & 8u) >> 1) | ((((uint32_t)lane >> 5) & 1u) << 3);

    // scatter sample loads issued first (deepest latency)
    float sv[4];
    #pragma unroll
    for (int mt = 0; mt < 4; ++mt)
        sv[mt] = samples[(size_t)(rowOff + r0 + mt * 16 + lm) * C_DIM + c];

    float b2r[4];
    #pragma unroll
    for (int nt = 0; nt < 4; ++nt) b2r[nt] = b2[(size_t)c * 64 + nt * 16 + lm];

    f32x4 acc[4][4];
    #pragma unroll
    for (int mt = 0; mt < 4; ++mt)
        #pragma unroll
        for (int nt = 0; nt < 4; ++nt)
            acc[mt][nt] = (f32x4){0.f, 0.f, 0.f, 0.f};

    #pragma unroll
    for (int ks = 0; ks < 2; ++ks) {
        const size_t wbase = ((size_t)c * 64) * 64 + ks * 32 + lg * 8;

        // rotating double-buffer of B-frags (hi only; static names, rule #20)
        short8 bhA = *(const short8*)(W2hi + wbase + (size_t)(0 * 16 + lm) * 64);
        short8 bhB = *(const short8*)(W2hi + wbase + (size_t)(1 * 16 + lm) * 64);

        // W1/b1 slices for this ks (k-contiguous 8 elems)
        const float4 w1a = *(const float4*)(W1 + (size_t)c * 64 + ks * 32 + lg * 8);
        const float4 w1b = *(const float4*)(W1 + (size_t)c * 64 + ks * 32 + lg * 8 + 4);
        const float4 b1a = *(const float4*)(b1 + (size_t)c * 64 + ks * 32 + lg * 8);
        const float4 b1b = *(const float4*)(b1 + (size_t)c * 64 + ks * 32 + lg * 8 + 4);
        const float w1r[8] = {w1a.x, w1a.y, w1a.z, w1a.w, w1b.x, w1b.y, w1b.z, w1b.w};
        const float b1r[8] = {b1a.x, b1a.y, b1a.z, b1a.w, b1b.x, b1b.y, b1b.z, b1b.w};

        // A-frags (VALU work overlaps the in-flight B loads)
        short8 afr[4];
        #pragma unroll
        for (int mt = 0; mt < 4; ++mt) {
            Frag8 af;
            #pragma unroll
            for (int j = 0; j < 8; ++j)
                af.s[j] = (short)bfbits(fmaxf(fmaf(sv[mt], w1r[j], b1r[j]), 0.f));
            afr[mt] = af.v;
        }

        // explicit schedule: MFMA(cur) then prefetch(next)
        {
            #pragma unroll
            for (int mt = 0; mt < 4; ++mt)
                acc[mt][0] = __builtin_amdgcn_mfma_f32_16x16x32_bf16(afr[mt], bhA, acc[mt][0], 0, 0, 0);
            bhA = *(const short8*)(W2hi + wbase + (size_t)(2 * 16 + lm) * 64);

            #pragma unroll
            for (int mt = 0; mt < 4; ++mt)
                acc[mt][1] = __builtin_amdgcn_mfma_f32_16x16x32_bf16(afr[mt], bhB, acc[mt][1], 0, 0, 0);
            bhB = *(const short8*)(W2hi + wbase + (size_t)(3 * 16 + lm) * 64);

            #pragma unroll
            for (int mt = 0; mt < 4; ++mt)
                acc[mt][2] = __builtin_amdgcn_mfma_f32_16x16x32_bf16(afr[mt], bhA, acc[mt][2], 0, 0, 0);

            #pragma unroll
            for (int mt = 0; mt < 4; ++mt)
                acc[mt][3] = __builtin_amdgcn_mfma_f32_16x16x32_bf16(afr[mt], bhB, acc[mt][3], 0, 0, 0);
        }
    }

    // add b2, sum of squares over f (lane-local over nt, butterfly over lm lanes)
    float rsc[4][4];
    #pragma unroll
    for (int mt = 0; mt < 4; ++mt)
        #pragma unroll
        for (int i = 0; i < 4; ++i) {
            float s2 = 0.f;
            #pragma unroll
            for (int nt = 0; nt < 4; ++nt) {
                float vv = acc[mt][nt][i] + b2r[nt];
                acc[mt][nt][i] = vv;
                s2 = fmaf(vv, vv, s2);
            }
            s2 += __shfl_xor(s2, 1); s2 += __shfl_xor(s2, 2);
            s2 += __shfl_xor(s2, 4); s2 += __shfl_xor(s2, 8);
            rsc[mt][i] = 1.f / fmaxf(sqrtf(s2), 1e-12f);
        }

    // two 32-row passes: repack into 32KB LDS, then coalesced writeout
    #pragma unroll
    for (int p = 0; p < 2; ++p) {
        if (p) __syncthreads();            // protect previous readout
        #pragma unroll
        for (int mh = 0; mh < 2; ++mh) {
            const int mt = p * 2 + mh;
            #pragma unroll
            for (int i = 0; i < 4; ++i) {
                const int rl = mh * 16 + lg * 4 + i;      // local row 0..31
                const uint32_t rowbase = (uint32_t)rl * 1024u;
                const uint32_t swz = (uint32_t)(rl & 7) << 4;
                #pragma unroll
                for (int nt = 0; nt < 4; ++nt) {
                    const int f = nt * 16 + lm;
                    const uint32_t bo = (rowbase + (uint32_t)f * 16u + (uint32_t)cl * 2u) ^ swz ^ xb;
                    *(unsigned short*)(sOut + bo) = bfbits(acc[mt][nt][i] * rsc[mt][i]);
                }
            }
        }
        __syncthreads();
        #pragma unroll
        for (int it = 0; it < 4; ++it) {
            const int unit = t + it * 512;
            const int rl = unit >> 6, f = unit & 63;
            const uint32_t lb = ((uint32_t)rl * 1024u + (uint32_t)f * 16u) ^ ((uint32_t)(rl & 7) << 4);
            uint4 val = *(const uint4*)(sOut + lb);
            // undo intra-unit XOR permutation (word j holds logical word j^sw):
            // sw bit1 = rl&8 (== it&1, compile-time), sw bit0 = f&8 (== t&8, per-lane)
            if (it & 1) val = make_uint4(val.z, val.w, val.x, val.y);
            {
                const bool s0 = (t & 8) != 0;
                const uint32_t a = s0 ? val.y : val.x;
                const uint32_t b = s0 ? val.x : val.y;
                const uint32_t cc2 = s0 ? val.w : val.z;
                const uint32_t d = s0 ? val.z : val.w;
                val = make_uint4(a, b, cc2, d);
            }
            ((uint4*)vbuf)[((size_t)(r0 + p * 32 + rl) * 16 + cg) * 64 + f] = val;
        }
    }
}

// ---------- K2: ctx GEMM, N-split for occupancy (R14-verified) ----------
__global__ __launch_bounds__(512) void k2_ctx(
        const unsigned short* __restrict__ whi,
        const uint32_t* __restrict__ vbuf, uint32_t* __restrict__ cbuf) {
    __shared__ char sC[65536];             // 4 rows x 16 KB
    const int t = threadIdx.x;
    const int lane = t & 63, wv = t >> 6;
    const int lm = lane & 15, lg = lane >> 4;
    const int rloc = wv >> 1, ch = wv & 1;
    const size_t rbase = (size_t)blockIdx.x * 4;
    const size_t r = rbase + rloc;
    const char* vrow = (const char*)vbuf + (r << 14);

#define LDA(KS, ET) (*(const short8*)(vrow + ((KS) * 4 + lg) * 1024 + ((ET) * 16 + lm) * 16))
#define LDW(KS, NT) (*(const short8*)(whi + (size_t)(ch * 64 + (NT) * 16 + lm) * C_DIM + (KS) * 32 + lg * 8))

    f32x4 acc[4][4];                       // [et][nt] -> 64 AGPRs
    #pragma unroll
    for (int et = 0; et < 4; ++et)
        #pragma unroll
        for (int nt = 0; nt < 4; ++nt)
            acc[et][nt] = (f32x4){0.f, 0.f, 0.f, 0.f};

    // A double-buffer (static names), w single-buffer
    short8 afX[4], afY[4], w0[4];
    #pragma unroll
    for (int et = 0; et < 4; ++et) afX[et] = LDA(0, et);
    #pragma unroll
    for (int et = 0; et < 4; ++et) afY[et] = LDA(1, et);
    #pragma unroll
    for (int nt = 0; nt < 4; ++nt) w0[nt] = LDW(0, nt);

#define K2_MFMA(AF)                                                                        \
    _Pragma("unroll")                                                                      \
    for (int nt = 0; nt < 4; ++nt)                                                         \
        _Pragma("unroll")                                                                  \
        for (int et = 0; et < 4; ++et)                                                     \
            acc[et][nt] = __builtin_amdgcn_mfma_f32_16x16x32_bf16(AF[et], w0[nt],          \
                                                                  acc[et][nt], 0, 0, 0);
    // ks = 0
    K2_MFMA(afX)
    #pragma unroll
    for (int et = 0; et < 4; ++et) afX[et] = LDA(2, et);
    #pragma unroll
    for (int nt = 0; nt < 4; ++nt) w0[nt] = LDW(1, nt);
    // ks = 1
    K2_MFMA(afY)
    #pragma unroll
    for (int et = 0; et < 4; ++et) afY[et] = LDA(3, et);
    #pragma unroll
    for (int nt = 0; nt < 4; ++nt) w0[nt] = LDW(2, nt);
    // ks = 2
    K2_MFMA(afX)
    #pragma unroll
    for (int nt = 0; nt < 4; ++nt) w0[nt] = LDW(3, nt);
    // ks = 3
    K2_MFMA(afY)
#undef K2_MFMA
#undef LDA
#undef LDW

    // stage ctx into LDS: [rloc][c][e] bf16, byte ^= ((c&7)<<4)
    char* srow = sC + rloc * 16384;
    #pragma unroll
    for (int et = 0; et < 4; ++et)
        #pragma unroll
        for (int nt = 0; nt < 4; ++nt) {
            const int cloc = ch * 64 + nt * 16 + lm;
            const uint32_t u0 = (uint32_t)bfbits(acc[et][nt][0]) | ((uint32_t)bfbits(acc[et][nt][1]) << 16);
            const uint32_t u1 = (uint32_t)bfbits(acc[et][nt][2]) | ((uint32_t)bfbits(acc[et][nt][3]) << 16);
            uint32_t bo = (uint32_t)cloc * 128u + (uint32_t)(et * 16 + lg * 4) * 2u;
            bo ^= (uint32_t)(cloc & 7) << 4;
            *(uint2*)(srow + bo) = make_uint2(u0, u1);
        }
    __syncthreads();

    // coalesced writeout: 64 KB = 4096 x 16B units; un-swizzle per unit
    #pragma unroll
    for (int it = 0; it < 8; ++it) {
        const int unit = t + it * 512;             // global 16B-unit in block tile
        const int row = unit >> 10;                // 1024 units per row
        const int u = unit & 1023;                 // c = u>>3, echunk = u&7
        const uint32_t lb = (uint32_t)row * 16384u +
                            (((uint32_t)u * 16u) ^ ((((uint32_t)u >> 3) & 7u) << 4));
        const uint4 val = *(const uint4*)(sC + lb);
        ((uint4*)cbuf)[((rbase + row) << 10) + u] = val;
    }
}

// ---------- K3: out = P2 . relu(P1 @ ctx + pb1) + pb2, MFMA, LDS-staged (R16-verified) ----------
// block = 64 rows x 8 columns, 8 waves (1 column each). M=r (4 tiles), N=f, K=e.
__global__ __launch_bounds__(512) void k3_out(
        const uint32_t* __restrict__ cbuf, const unsigned short* __restrict__ P1hi,
        const unsigned short* __restrict__ P1lo, const float* __restrict__ pb1,
        const float* __restrict__ P2, const float* __restrict__ pb2,
        float* __restrict__ out, int rowOff) {
    __shared__ char sC[64 * 1024];          // [r][c_local][e] bf16, 64KB, XOR-swizzled
    const int t = threadIdx.x;
    const int cg = blockIdx.x;              // 16 groups of 8 columns
    const int r0 = blockIdx.y * 64;         // chunk-local
    const int lane = t & 63, wv = t >> 6;
    const int lm = lane & 15, lg = lane >> 4;
    const int cl = wv;
    const int c = cg * 8 + cl;

    // stage ctx[r0..r0+63][cg*8..+8][all e] coalesced: 1KB contiguous per row
    {
        const int rr = t >> 6;              // 8 rows per pass
        const int inner = t & 63;           // 16B chunk within the 1KB c-window
        #pragma unroll
        for (int p = 0; p < 8; ++p) {
            const int r = p * 8 + rr;
            const uint4 val = *(const uint4*)((const char*)cbuf +
                (size_t)(r0 + r) * 16384 + (size_t)cg * 1024 + (size_t)inner * 16);
            const uint32_t bo = ((uint32_t)r * 1024u + (uint32_t)inner * 16u) ^ ((uint32_t)(r & 7) << 4);
            *(uint4*)(sC + bo) = val;
        }
    }
    __syncthreads();

    float pb1r[4], p2r[4];
    #pragma unroll
    for (int nt = 0; nt < 4; ++nt) {
        pb1r[nt] = pb1[(size_t)c * 64 + nt * 16 + lm];
        p2r[nt]  = P2[(size_t)c * 64 + nt * 16 + lm];
    }
    const float pb2c = pb2[c];

    f32x4 acc[4][4];                        // [mt][nt]
    #pragma unroll
    for (int mt = 0; mt < 4; ++mt)
        #pragma unroll
        for (int nt = 0; nt < 4; ++nt)
            acc[mt][nt] = (f32x4){0.f, 0.f, 0.f, 0.f};

    #pragma unroll
    for (int ks = 0; ks < 2; ++ks) {
        short8 a[4];
        #pragma unroll
        for (int mt = 0; mt < 4; ++mt) {
            const int rl = mt * 16 + lm;
            const uint32_t bo = ((uint32_t)rl * 1024u + (uint32_t)cl * 128u +
                                 (uint32_t)ks * 64u + (uint32_t)lg * 16u) ^ ((uint32_t)(rl & 7) << 4);
            a[mt] = *(const short8*)(sC + bo);
        }
        #pragma unroll
        for (int nt = 0; nt < 4; ++nt) {
            const size_t wb = ((size_t)c * 64 + nt * 16 + lm) * 64 + ks * 32 + lg * 8;
            const short8 bh = *(const short8*)(P1hi + wb);
            const short8 bl = *(const short8*)(P1lo + wb);
            #pragma unroll
            for (int mt = 0; mt < 4; ++mt) {
                acc[mt][nt] = __builtin_amdgcn_mfma_f32_16x16x32_bf16(a[mt], bh, acc[mt][nt], 0, 0, 0);
                acc[mt][nt] = __builtin_amdgcn_mfma_f32_16x16x32_bf16(a[mt], bl, acc[mt][nt], 0, 0, 0);
            }
        }
    }

    // epilogue: relu, dot with P2 over f (lane-local nt + butterfly over lm), store
    #pragma unroll
    for (int mt = 0; mt < 4; ++mt)
        #pragma unroll
        for (int i = 0; i < 4; ++i) {
            float p = 0.f;
            #pragma unroll
            for (int nt = 0; nt < 4; ++nt)
                p = fmaf(fmaxf(acc[mt][nt][i] + pb1r[nt], 0.f), p2r[nt], p);
            p += __shfl_xor(p, 1); p += __shfl_xor(p, 2);
            p += __shfl_xor(p, 4); p += __shfl_xor(p, 8);
            if (lm == 0)
                out[(size_t)(rowOff + r0 + mt * 16 + lg * 4 + i) * C_DIM + c] = p + pb2c;
        }
}

// ---------- host ----------
extern "C" void kernel_launch(void* const* d_in, const int* in_sizes, int n_in,
                              void* d_out, int out_size, void* d_ws, size_t ws_size,
                              hipStream_t stream) {
    const float* samples = (const float*)d_in[0];
    const float* W1  = (const float*)d_in[1];
    const float* b1  = (const float*)d_in[2];
    const float* W2  = (const float*)d_in[3];
    const float* b2  = (const float*)d_in[4];
    const float* q   = (const float*)d_in[5];
    const float* P1  = (const float*)d_in[6];
    const float* pb1 = (const float*)d_in[7];
    const float* P2  = (const float*)d_in[8];
    const float* pb2 = (const float*)d_in[9];
    float* out = (float*)d_out;

    char* ws = (char*)d_ws;
    unsigned short* whi  = (unsigned short*)ws;                       // 32KB
    unsigned short* wlo  = (unsigned short*)(ws + 32768);             // 32KB (k0 side product)
    unsigned short* W2hi = (unsigned short*)(ws + 65536);             // 1MB (hi only)
    unsigned short* P1hi = (unsigned short*)(ws + 65536 + 2097152);   // 1MB
    unsigned short* P1lo = (unsigned short*)(ws + 65536 + 3145728);   // 1MB
    const size_t head = 65536 + 4194304;

    // two regions: V and ctx, each maxRows*16KB (full-batch chunking, R14/R16 best)
    size_t avail = (ws_size > head) ? ws_size - head : 0;
    long maxRows = (long)(avail / ((size_t)2 * C_DIM * E_DIM * 2));
    maxRows = (maxRows / 256) * 256;
    if (maxRows > B_DIM) maxRows = B_DIM;
    if (maxRows < 256) maxRows = 256;

    uint32_t* vbuf = (uint32_t*)(ws + head);
    uint32_t* cbuf = (uint32_t*)(ws + head + (size_t)maxRows * 16384);

    k0_softmax<<<dim3(C_DIM), dim3(C_DIM), 0, stream>>>(q, whi, wlo);
    kP_hi<<<dim3(512), 256, 0, stream>>>(W2, W2hi);            // W2: hi only (lo unused)
    kP_split<<<dim3(512), 256, 0, stream>>>(P1, P1hi, P1lo);

    for (int off = 0; off < B_DIM; off += (int)maxRows) {
        const int rows = (int)(((long)(B_DIM - off) < maxRows) ? (long)(B_DIM - off) : maxRows);
        k1_value<<<dim3(rows / 64, 16), 512, 0, stream>>>(samples, W1, b1, W2hi, b2, vbuf, off);
        k2_ctx<<<dim3(rows / 4), 512, 0, stream>>>(whi, vbuf, cbuf);
        k3_out<<<dim3(16, rows / 64), 512, 0, stream>>>(cbuf, P1hi, P1lo, pb1, P2, pb2, out, off);
    }
}

// Round 22
// 191.143 us; speedup vs baseline: 1.4927x; 1.1598x over previous
//
#include <hip/hip_runtime.h>
#include <hip/hip_bf16.h>
#include <cstdint>

#define C_DIM 128
#define E_DIM 64
#define B_DIM 8192

typedef __attribute__((ext_vector_type(8))) short short8;
typedef __attribute__((ext_vector_type(4))) float f32x4;

union Frag8 { short8 v; short s[8]; uint32_t u[4]; };

__device__ __forceinline__ unsigned short bfbits(float x) {
    union { __hip_bfloat16 h; unsigned short u; } cv;
    cv.h = __float2bfloat16(x);
    return cv.u;
}
__device__ __forceinline__ float bits2f(unsigned short b) {
    return __uint_as_float(((uint32_t)b) << 16);
}

// ---------- K0: w = softmax(q,axis=1), zero diag, split hi/lo bf16, layout [c][n] ----------
__global__ __launch_bounds__(128) void k0_softmax(const float* __restrict__ q,
                                                  unsigned short* __restrict__ whi,
                                                  unsigned short* __restrict__ wlo) {
    const int c = blockIdx.x;
    const int t = threadIdx.x;            // n
    __shared__ float redM[2], redS[2];
    float v = q[c * C_DIM + t];
    float m = v;
    #pragma unroll
    for (int o = 32; o > 0; o >>= 1) m = fmaxf(m, __shfl_xor(m, o));
    if ((t & 63) == 0) redM[t >> 6] = m;
    __syncthreads();
    m = fmaxf(redM[0], redM[1]);
    float e = expf(v - m);
    float s = e;
    #pragma unroll
    for (int o = 32; o > 0; o >>= 1) s += __shfl_xor(s, o);
    if ((t & 63) == 0) redS[t >> 6] = s;
    __syncthreads();
    s = redS[0] + redS[1];
    float w = e / s;
    if (t == c) w = 0.f;                  // zero diagonal AFTER softmax
    unsigned short hb = bfbits(w);
    whi[c * C_DIM + t] = hb;
    wlo[c * C_DIM + t] = bfbits(w - bits2f(hb));
}

// ---------- KPh: hi-only bf16 cast (lo halves unused since R16/R22) ----------
__global__ __launch_bounds__(256) void kP_hi(const float* __restrict__ src,
                                             unsigned short* __restrict__ hi) {
    const int i = blockIdx.x * 256 + threadIdx.x;   // index in float4 units
    const float4 v = ((const float4*)src)[i];
    ((ushort4*)hi)[i] = make_ushort4(bfbits(v.x), bfbits(v.y), bfbits(v.z), bfbits(v.w));
}

// ---------- K1: value MLP + L2 norm, MFMA. Output V[r][n8][e][8n] bf16 ----------
// block = 64 rows x 8 columns, 8 waves (1 column each). D: m=r, n=f.
// W2 hi-only; repack XOR-spreads banks; readout un-permutes (R16-verified).
__global__ __launch_bounds__(512, 4) void k1_value(
        const float* __restrict__ samples, const float* __restrict__ W1,
        const float* __restrict__ b1, const unsigned short* __restrict__ W2hi,
        const float* __restrict__ b2,
        uint32_t* __restrict__ vbuf, int rowOff) {
    __shared__ char sOut[32 * 1024];       // [r32][f][c_local] bf16, XOR-swizzled
    const int t = threadIdx.x;
    const int rt = blockIdx.x, cg = blockIdx.y;
    const int r0 = rt * 64;
    const int cl = t >> 6;                 // wave = local column
    const int lane = t & 63;
    const int lm = lane & 15, lg = lane >> 4;
    const int c = cg * 8 + cl;
    // per-thread bank-spread XOR: bit2 = f&8 (= lane&8), bit3 = rl&8 (= lg bit1)
    const uint32_t xb = (((uint32_t)lane & 8u) >> 1) | ((((uint32_t)lane >> 5) & 1u) << 3);

    // scatter sample loads issued first (deepest latency)
    float sv[4];
    #pragma unroll
    for (int mt = 0; mt < 4; ++mt)
        sv[mt] = samples[(size_t)(rowOff + r0 + mt * 16 + lm) * C_DIM + c];

    float b2r[4];
    #pragma unroll
    for (int nt = 0; nt < 4; ++nt) b2r[nt] = b2[(size_t)c * 64 + nt * 16 + lm];

    f32x4 acc[4][4];
    #pragma unroll
    for (int mt = 0; mt < 4; ++mt)
        #pragma unroll
        for (int nt = 0; nt < 4; ++nt)
            acc[mt][nt] = (f32x4){0.f, 0.f, 0.f, 0.f};

    #pragma unroll
    for (int ks = 0; ks < 2; ++ks) {
        const size_t wbase = ((size_t)c * 64) * 64 + ks * 32 + lg * 8;

        // rotating double-buffer of B-frags (hi only; static names, rule #20)
        short8 bhA = *(const short8*)(W2hi + wbase + (size_t)(0 * 16 + lm) * 64);
        short8 bhB = *(const short8*)(W2hi + wbase + (size_t)(1 * 16 + lm) * 64);

        // W1/b1 slices for this ks (k-contiguous 8 elems)
        const float4 w1a = *(const float4*)(W1 + (size_t)c * 64 + ks * 32 + lg * 8);
        const float4 w1b = *(const float4*)(W1 + (size_t)c * 64 + ks * 32 + lg * 8 + 4);
        const float4 b1a = *(const float4*)(b1 + (size_t)c * 64 + ks * 32 + lg * 8);
        const float4 b1b = *(const float4*)(b1 + (size_t)c * 64 + ks * 32 + lg * 8 + 4);
        const float w1r[8] = {w1a.x, w1a.y, w1a.z, w1a.w, w1b.x, w1b.y, w1b.z, w1b.w};
        const float b1r[8] = {b1a.x, b1a.y, b1a.z, b1a.w, b1b.x, b1b.y, b1b.z, b1b.w};

        // A-frags (VALU work overlaps the in-flight B loads)
        short8 afr[4];
        #pragma unroll
        for (int mt = 0; mt < 4; ++mt) {
            Frag8 af;
            #pragma unroll
            for (int j = 0; j < 8; ++j)
                af.s[j] = (short)bfbits(fmaxf(fmaf(sv[mt], w1r[j], b1r[j]), 0.f));
            afr[mt] = af.v;
        }

        // explicit schedule: MFMA(cur) then prefetch(next)
        {
            #pragma unroll
            for (int mt = 0; mt < 4; ++mt)
                acc[mt][0] = __builtin_amdgcn_mfma_f32_16x16x32_bf16(afr[mt], bhA, acc[mt][0], 0, 0, 0);
            bhA = *(const short8*)(W2hi + wbase + (size_t)(2 * 16 + lm) * 64);

            #pragma unroll
            for (int mt = 0; mt < 4; ++mt)
                acc[mt][1] = __builtin_amdgcn_mfma_f32_16x16x32_bf16(afr[mt], bhB, acc[mt][1], 0, 0, 0);
            bhB = *(const short8*)(W2hi + wbase + (size_t)(3 * 16 + lm) * 64);

            #pragma unroll
            for (int mt = 0; mt < 4; ++mt)
                acc[mt][2] = __builtin_amdgcn_mfma_f32_16x16x32_bf16(afr[mt], bhA, acc[mt][2], 0, 0, 0);

            #pragma unroll
            for (int mt = 0; mt < 4; ++mt)
                acc[mt][3] = __builtin_amdgcn_mfma_f32_16x16x32_bf16(afr[mt], bhB, acc[mt][3], 0, 0, 0);
        }
    }

    // add b2, sum of squares over f (lane-local over nt, butterfly over lm lanes)
    float rsc[4][4];
    #pragma unroll
    for (int mt = 0; mt < 4; ++mt)
        #pragma unroll
        for (int i = 0; i < 4; ++i) {
            float s2 = 0.f;
            #pragma unroll
            for (int nt = 0; nt < 4; ++nt) {
                float vv = acc[mt][nt][i] + b2r[nt];
                acc[mt][nt][i] = vv;
                s2 = fmaf(vv, vv, s2);
            }
            s2 += __shfl_xor(s2, 1); s2 += __shfl_xor(s2, 2);
            s2 += __shfl_xor(s2, 4); s2 += __shfl_xor(s2, 8);
            rsc[mt][i] = 1.f / fmaxf(sqrtf(s2), 1e-12f);
        }

    // two 32-row passes: repack into 32KB LDS, then coalesced writeout
    #pragma unroll
    for (int p = 0; p < 2; ++p) {
        if (p) __syncthreads();            // protect previous readout
        #pragma unroll
        for (int mh = 0; mh < 2; ++mh) {
            const int mt = p * 2 + mh;
            #pragma unroll
            for (int i = 0; i < 4; ++i) {
                const int rl = mh * 16 + lg * 4 + i;      // local row 0..31
                const uint32_t rowbase = (uint32_t)rl * 1024u;
                const uint32_t swz = (uint32_t)(rl & 7) << 4;
                #pragma unroll
                for (int nt = 0; nt < 4; ++nt) {
                    const int f = nt * 16 + lm;
                    const uint32_t bo = (rowbase + (uint32_t)f * 16u + (uint32_t)cl * 2u) ^ swz ^ xb;
                    *(unsigned short*)(sOut + bo) = bfbits(acc[mt][nt][i] * rsc[mt][i]);
                }
            }
        }
        __syncthreads();
        #pragma unroll
        for (int it = 0; it < 4; ++it) {
            const int unit = t + it * 512;
            const int rl = unit >> 6, f = unit & 63;
            const uint32_t lb = ((uint32_t)rl * 1024u + (uint32_t)f * 16u) ^ ((uint32_t)(rl & 7) << 4);
            uint4 val = *(const uint4*)(sOut + lb);
            // undo intra-unit XOR permutation (word j holds logical word j^sw):
            // sw bit1 = rl&8 (== it&1, compile-time), sw bit0 = f&8 (== t&8, per-lane)
            if (it & 1) val = make_uint4(val.z, val.w, val.x, val.y);
            {
                const bool s0 = (t & 8) != 0;
                const uint32_t a = s0 ? val.y : val.x;
                const uint32_t b = s0 ? val.x : val.y;
                const uint32_t cc2 = s0 ? val.w : val.z;
                const uint32_t d = s0 ? val.z : val.w;
                val = make_uint4(a, b, cc2, d);
            }
            ((uint4*)vbuf)[((size_t)(r0 + p * 32 + rl) * 16 + cg) * 64 + f] = val;
        }
    }
}

// ---------- K2: ctx GEMM, N-split for occupancy (R14-verified) ----------
__global__ __launch_bounds__(512) void k2_ctx(
        const unsigned short* __restrict__ whi,
        const uint32_t* __restrict__ vbuf, uint32_t* __restrict__ cbuf) {
    __shared__ char sC[65536];             // 4 rows x 16 KB
    const int t = threadIdx.x;
    const int lane = t & 63, wv = t >> 6;
    const int lm = lane & 15, lg = lane >> 4;
    const int rloc = wv >> 1, ch = wv & 1;
    const size_t rbase = (size_t)blockIdx.x * 4;
    const size_t r = rbase + rloc;
    const char* vrow = (const char*)vbuf + (r << 14);

#define LDA(KS, ET) (*(const short8*)(vrow + ((KS) * 4 + lg) * 1024 + ((ET) * 16 + lm) * 16))
#define LDW(KS, NT) (*(const short8*)(whi + (size_t)(ch * 64 + (NT) * 16 + lm) * C_DIM + (KS) * 32 + lg * 8))

    f32x4 acc[4][4];                       // [et][nt] -> 64 AGPRs
    #pragma unroll
    for (int et = 0; et < 4; ++et)
        #pragma unroll
        for (int nt = 0; nt < 4; ++nt)
            acc[et][nt] = (f32x4){0.f, 0.f, 0.f, 0.f};

    // A double-buffer (static names), w single-buffer
    short8 afX[4], afY[4], w0[4];
    #pragma unroll
    for (int et = 0; et < 4; ++et) afX[et] = LDA(0, et);
    #pragma unroll
    for (int et = 0; et < 4; ++et) afY[et] = LDA(1, et);
    #pragma unroll
    for (int nt = 0; nt < 4; ++nt) w0[nt] = LDW(0, nt);

#define K2_MFMA(AF)                                                                        \
    _Pragma("unroll")                                                                      \
    for (int nt = 0; nt < 4; ++nt)                                                         \
        _Pragma("unroll")                                                                  \
        for (int et = 0; et < 4; ++et)                                                     \
            acc[et][nt] = __builtin_amdgcn_mfma_f32_16x16x32_bf16(AF[et], w0[nt],          \
                                                                  acc[et][nt], 0, 0, 0);
    // ks = 0
    K2_MFMA(afX)
    #pragma unroll
    for (int et = 0; et < 4; ++et) afX[et] = LDA(2, et);
    #pragma unroll
    for (int nt = 0; nt < 4; ++nt) w0[nt] = LDW(1, nt);
    // ks = 1
    K2_MFMA(afY)
    #pragma unroll
    for (int et = 0; et < 4; ++et) afY[et] = LDA(3, et);
    #pragma unroll
    for (int nt = 0; nt < 4; ++nt) w0[nt] = LDW(2, nt);
    // ks = 2
    K2_MFMA(afX)
    #pragma unroll
    for (int nt = 0; nt < 4; ++nt) w0[nt] = LDW(3, nt);
    // ks = 3
    K2_MFMA(afY)
#undef K2_MFMA
#undef LDA
#undef LDW

    // stage ctx into LDS: [rloc][c][e] bf16, byte ^= ((c&7)<<4)
    char* srow = sC + rloc * 16384;
    #pragma unroll
    for (int et = 0; et < 4; ++et)
        #pragma unroll
        for (int nt = 0; nt < 4; ++nt) {
            const int cloc = ch * 64 + nt * 16 + lm;
            const uint32_t u0 = (uint32_t)bfbits(acc[et][nt][0]) | ((uint32_t)bfbits(acc[et][nt][1]) << 16);
            const uint32_t u1 = (uint32_t)bfbits(acc[et][nt][2]) | ((uint32_t)bfbits(acc[et][nt][3]) << 16);
            uint32_t bo = (uint32_t)cloc * 128u + (uint32_t)(et * 16 + lg * 4) * 2u;
            bo ^= (uint32_t)(cloc & 7) << 4;
            *(uint2*)(srow + bo) = make_uint2(u0, u1);
        }
    __syncthreads();

    // coalesced writeout: 64 KB = 4096 x 16B units; un-swizzle per unit
    #pragma unroll
    for (int it = 0; it < 8; ++it) {
        const int unit = t + it * 512;             // global 16B-unit in block tile
        const int row = unit >> 10;                // 1024 units per row
        const int u = unit & 1023;                 // c = u>>3, echunk = u&7
        const uint32_t lb = (uint32_t)row * 16384u +
                            (((uint32_t)u * 16u) ^ ((((uint32_t)u >> 3) & 7u) << 4));
        const uint4 val = *(const uint4*)(sC + lb);
        ((uint4*)cbuf)[((rbase + row) << 10) + u] = val;
    }
}

// ---------- K3: out = P2 . relu(P1 @ ctx + pb1) + pb2, MFMA, LDS-staged ----------
// R16 structure; P1 hi-only (same transformation validated on w in R11 and W2
// in R16 with absmax unchanged) -> halves B-frag loads and MFMAs per wave.
__global__ __launch_bounds__(512) void k3_out(
        const uint32_t* __restrict__ cbuf, const unsigned short* __restrict__ P1hi,
        const float* __restrict__ pb1,
        const float* __restrict__ P2, const float* __restrict__ pb2,
        float* __restrict__ out, int rowOff) {
    __shared__ char sC[64 * 1024];          // [r][c_local][e] bf16, 64KB, XOR-swizzled
    const int t = threadIdx.x;
    const int cg = blockIdx.x;              // 16 groups of 8 columns
    const int r0 = blockIdx.y * 64;         // chunk-local
    const int lane = t & 63, wv = t >> 6;
    const int lm = lane & 15, lg = lane >> 4;
    const int cl = wv;
    const int c = cg * 8 + cl;

    // stage ctx[r0..r0+63][cg*8..+8][all e] coalesced: 1KB contiguous per row
    {
        const int rr = t >> 6;              // 8 rows per pass
        const int inner = t & 63;           // 16B chunk within the 1KB c-window
        #pragma unroll
        for (int p = 0; p < 8; ++p) {
            const int r = p * 8 + rr;
            const uint4 val = *(const uint4*)((const char*)cbuf +
                (size_t)(r0 + r) * 16384 + (size_t)cg * 1024 + (size_t)inner * 16);
            const uint32_t bo = ((uint32_t)r * 1024u + (uint32_t)inner * 16u) ^ ((uint32_t)(r & 7) << 4);
            *(uint4*)(sC + bo) = val;
        }
    }
    __syncthreads();

    float pb1r[4], p2r[4];
    #pragma unroll
    for (int nt = 0; nt < 4; ++nt) {
        pb1r[nt] = pb1[(size_t)c * 64 + nt * 16 + lm];
        p2r[nt]  = P2[(size_t)c * 64 + nt * 16 + lm];
    }
    const float pb2c = pb2[c];

    f32x4 acc[4][4];                        // [mt][nt]
    #pragma unroll
    for (int mt = 0; mt < 4; ++mt)
        #pragma unroll
        for (int nt = 0; nt < 4; ++nt)
            acc[mt][nt] = (f32x4){0.f, 0.f, 0.f, 0.f};

    #pragma unroll
    for (int ks = 0; ks < 2; ++ks) {
        short8 a[4];
        #pragma unroll
        for (int mt = 0; mt < 4; ++mt) {
            const int rl = mt * 16 + lm;
            const uint32_t bo = ((uint32_t)rl * 1024u + (uint32_t)cl * 128u +
                                 (uint32_t)ks * 64u + (uint32_t)lg * 16u) ^ ((uint32_t)(rl & 7) << 4);
            a[mt] = *(const short8*)(sC + bo);
        }
        #pragma unroll
        for (int nt = 0; nt < 4; ++nt) {
            const size_t wb = ((size_t)c * 64 + nt * 16 + lm) * 64 + ks * 32 + lg * 8;
            const short8 bh = *(const short8*)(P1hi + wb);
            #pragma unroll
            for (int mt = 0; mt < 4; ++mt)
                acc[mt][nt] = __builtin_amdgcn_mfma_f32_16x16x32_bf16(a[mt], bh, acc[mt][nt], 0, 0, 0);
        }
    }

    // epilogue: relu, dot with P2 over f (lane-local nt + butterfly over lm), store
    #pragma unroll
    for (int mt = 0; mt < 4; ++mt)
        #pragma unroll
        for (int i = 0; i < 4; ++i) {
            float p = 0.f;
            #pragma unroll
            for (int nt = 0; nt < 4; ++nt)
                p = fmaf(fmaxf(acc[mt][nt][i] + pb1r[nt], 0.f), p2r[nt], p);
            p += __shfl_xor(p, 1); p += __shfl_xor(p, 2);
            p += __shfl_xor(p, 4); p += __shfl_xor(p, 8);
            if (lm == 0)
                out[(size_t)(rowOff + r0 + mt * 16 + lg * 4 + i) * C_DIM + c] = p + pb2c;
        }
}

// ---------- host ----------
extern "C" void kernel_launch(void* const* d_in, const int* in_sizes, int n_in,
                              void* d_out, int out_size, void* d_ws, size_t ws_size,
                              hipStream_t stream) {
    const float* samples = (const float*)d_in[0];
    const float* W1  = (const float*)d_in[1];
    const float* b1  = (const float*)d_in[2];
    const float* W2  = (const float*)d_in[3];
    const float* b2  = (const float*)d_in[4];
    const float* q   = (const float*)d_in[5];
    const float* P1  = (const float*)d_in[6];
    const float* pb1 = (const float*)d_in[7];
    const float* P2  = (const float*)d_in[8];
    const float* pb2 = (const float*)d_in[9];
    float* out = (float*)d_out;

    char* ws = (char*)d_ws;
    unsigned short* whi  = (unsigned short*)ws;                       // 32KB
    unsigned short* wlo  = (unsigned short*)(ws + 32768);             // 32KB (k0 side product)
    unsigned short* W2hi = (unsigned short*)(ws + 65536);             // 1MB (hi only)
    unsigned short* P1hi = (unsigned short*)(ws + 65536 + 2097152);   // 1MB (hi only)
    const size_t head = 65536 + 4194304;

    // two regions: V and ctx, each maxRows*16KB (full-batch chunking, R14/R16 best)
    size_t avail = (ws_size > head) ? ws_size - head : 0;
    long maxRows = (long)(avail / ((size_t)2 * C_DIM * E_DIM * 2));
    maxRows = (maxRows / 256) * 256;
    if (maxRows > B_DIM) maxRows = B_DIM;
    if (maxRows < 256) maxRows = 256;

    uint32_t* vbuf = (uint32_t*)(ws + head);
    uint32_t* cbuf = (uint32_t*)(ws + head + (size_t)maxRows * 16384);

    k0_softmax<<<dim3(C_DIM), dim3(C_DIM), 0, stream>>>(q, whi, wlo);
    kP_hi<<<dim3(512), 256, 0, stream>>>(W2, W2hi);            // W2: hi only
    kP_hi<<<dim3(512), 256, 0, stream>>>(P1, P1hi);            // P1: hi only

    for (int off = 0; off < B_DIM; off += (int)maxRows) {
        const int rows = (int)(((long)(B_DIM - off) < maxRows) ? (long)(B_DIM - off) : maxRows);
        k1_value<<<dim3(rows / 64, 16), 512, 0, stream>>>(samples, W1, b1, W2hi, b2, vbuf, off);
        k2_ctx<<<dim3(rows / 4), 512, 0, stream>>>(whi, vbuf, cbuf);
        k3_out<<<dim3(16, rows / 64), 512, 0, stream>>>(cbuf, P1hi, pb1, P2, pb2, out, off);
    }
}